// Round 1
// baseline (53.083 us; speedup 1.0000x reference)
//
#include <hip/hip_runtime.h>

#define BB 4
#define NN 32
#define CC 32
#define HWD 4096
#define SPLIT 4
#define CHUNK 1024   // hw per k_gram block
#define SUB 128      // hw per LDS tile in k_gram

// async global->LDS, 16B per lane, LDS dest = wave-uniform base + lane*16
__device__ __forceinline__ void gld_lds16(float* lds, const float* g) {
    __builtin_amdgcn_global_load_lds(
        (const __attribute__((address_space(1))) void*)g,
        (__attribute__((address_space(3))) void*)lds,
        16, 0, 0);
}

// ---------------- Kernel 1: Gram partials G[bc][s][a][f] ----------------
__global__ __launch_bounds__(256) void k_gram(const float* __restrict__ x,
                                              float* __restrict__ Gp) {
    const int bid = blockIdx.x;            // 0..511
    const int s   = bid & (SPLIT - 1);
    const int bc  = bid >> 2;              // 0..127
    const int b   = bc >> 5, c = bc & 31;
    const int tid = threadIdx.x;
    const int wv  = tid >> 6;              // wave id 0..3 (hw subgroup)
    const int pos = tid & 63;
    const int pa  = pos >> 3;              // 0..7 -> a base 4*pa
    const int pf  = pos & 7;               // 0..7 -> f base 4*pf

    __shared__ __align__(16) float tile[SUB][36];   // [hw][a], pad->36 (bank-safe)
    __shared__ __align__(16) float red[4 * 64 * 16];

    const float* xb = x + ((size_t)(b * NN) * CC + c) * HWD + s * CHUNK;
    const size_t arow = (size_t)CC * HWD;  // stride between a-rows (floats)

    float acc[4][4];
#pragma unroll
    for (int i = 0; i < 4; ++i)
#pragma unroll
        for (int j = 0; j < 4; ++j) acc[i][j] = 0.f;

    const int la = tid >> 3;   // 0..31 : a row this thread loads
    const int t7 = tid & 7;

    for (int ch = 0; ch < CHUNK / SUB; ++ch) {
        __syncthreads();   // tile reuse safety
#pragma unroll
        for (int k = 0; k < 4; ++k) {
            const int q = t7 + 8 * k;   // hw quad 0..31
            const float4 v = *(const float4*)(xb + (size_t)la * arow + ch * SUB + 4 * q);
            tile[4 * q + 0][la] = v.x;
            tile[4 * q + 1][la] = v.y;
            tile[4 * q + 2][la] = v.z;
            tile[4 * q + 3][la] = v.w;
        }
        __syncthreads();
        // wave wv handles hw_local = wv*32 .. wv*32+31
#pragma unroll 8
        for (int h = 0; h < 32; ++h) {
            const int hw = wv * 32 + h;
            const float4 va = *(const float4*)&tile[hw][4 * pa];
            const float4 vf = *(const float4*)&tile[hw][4 * pf];
            float xa[4] = {va.x, va.y, va.z, va.w};
            float xf[4] = {vf.x, vf.y, vf.z, vf.w};
#pragma unroll
            for (int i = 0; i < 4; ++i)
#pragma unroll
                for (int j = 0; j < 4; ++j)
                    acc[i][j] = fmaf(xa[i], xf[j], acc[i][j]);
        }
    }

    // block reduction over the 4 hw-subgroup waves
#pragma unroll
    for (int i = 0; i < 4; ++i)
#pragma unroll
        for (int j = 0; j < 4; ++j)
            red[wv * 1024 + pos * 16 + i * 4 + j] = acc[i][j];
    __syncthreads();

    // thread t writes G indices 4t..4t+3 (G = a*32+f), coalesced float4
    const int t   = tid;
    const int pa2 = t >> 5;
    const int i2  = (t >> 3) & 3;
    const int pf2 = t & 7;
    const int P   = (pa2 * 8 + pf2) * 16 + i2 * 4;
    float4 sum = make_float4(0.f, 0.f, 0.f, 0.f);
#pragma unroll
    for (int w2 = 0; w2 < 4; ++w2) {
        const float4 v = *(const float4*)&red[w2 * 1024 + P];
        sum.x += v.x; sum.y += v.y; sum.z += v.z; sum.w += v.w;
    }
    *(float4*)&Gp[(size_t)bid * 1024 + 4 * t] = sum;
}

// ---------------- Kernel 2: reduce splits + scale + softmax + wv ----------------
__global__ __launch_bounds__(64) void k_softmax(const float* __restrict__ Gp,
                                                const float* __restrict__ w,
                                                float* __restrict__ Ahat) {
    const int bc = blockIdx.x;        // 0..127
    const int c  = bc & 31;
    const int a  = threadIdx.x;
    if (a >= 32) return;

    const float wq = w[(a * CC + c) * 3 + 0] * 0.015625f;  // scale = 1/sqrt(4096)
    float S[32];
#pragma unroll
    for (int f = 0; f < 32; ++f) {
        float g = 0.f;
#pragma unroll
        for (int s = 0; s < SPLIT; ++s)
            g += Gp[(size_t)(bc * SPLIT + s) * 1024 + a * 32 + f];
        const float wk = w[(f * CC + c) * 3 + 1];
        S[f] = wq * wk * g;
    }
    float m = S[0];
#pragma unroll
    for (int f = 1; f < 32; ++f) m = fmaxf(m, S[f]);
    float sum = 0.f;
#pragma unroll
    for (int f = 0; f < 32; ++f) { S[f] = __expf(S[f] - m); sum += S[f]; }
    const float inv = 1.f / sum;
#pragma unroll
    for (int f = 0; f < 32; ++f) {
        const float wvv = w[(f * CC + c) * 3 + 2];
        Ahat[(size_t)bc * 1024 + a * 32 + f] = S[f] * inv * wvv;
    }
}

// ---------------- Kernel 3: out[a,b,c,hw] = sum_f Ahat[a,f] * x[b,f,c,hw] ----------------
__global__ __launch_bounds__(256) void k_pv(const float* __restrict__ x,
                                            const float* __restrict__ Ahat,
                                            float* __restrict__ out) {
    const int bid = blockIdx.x;        // 0..2047
    const int ch  = bid & 15;          // hw chunk of 256
    const int bc  = bid >> 4;
    const int b   = bc >> 5, c = bc & 31;
    const int tid = threadIdx.x;
    const int wv  = tid >> 6;          // wave id 0..3 == a-tile
    const int ln  = tid & 63;
    const int q   = ln;                // hw quad 0..63

    __shared__ __align__(16) float XL[32][256];
    __shared__ __align__(16) float AL[1024];

    const float* xbase = x + ((size_t)(b * NN) * CC + c) * HWD + ch * 256;
    const size_t frow = (size_t)CC * HWD;
#pragma unroll
    for (int k = 0; k < 8; ++k) {
        const int f = k * 4 + wv;      // one 1KB row per wave-load
        gld_lds16(&XL[f][0], xbase + (size_t)f * frow + ln * 4);
    }
    gld_lds16(&AL[wv * 256], Ahat + (size_t)bc * 1024 + wv * 256 + ln * 4);
    __syncthreads();

    float acc[8][4];
#pragma unroll
    for (int i = 0; i < 8; ++i)
#pragma unroll
        for (int j = 0; j < 4; ++j) acc[i][j] = 0.f;

#pragma unroll
    for (int f = 0; f < 32; ++f) {
        const float4 xv = *(const float4*)&XL[f][4 * q];
#pragma unroll
        for (int i = 0; i < 8; ++i) {
            const float av = AL[(8 * wv + i) * 32 + f];   // broadcast
            acc[i][0] = fmaf(av, xv.x, acc[i][0]);
            acc[i][1] = fmaf(av, xv.y, acc[i][1]);
            acc[i][2] = fmaf(av, xv.z, acc[i][2]);
            acc[i][3] = fmaf(av, xv.w, acc[i][3]);
        }
    }

#pragma unroll
    for (int i = 0; i < 8; ++i) {
        const int a = 8 * wv + i;
        const float4 v = make_float4(acc[i][0], acc[i][1], acc[i][2], acc[i][3]);
        *(float4*)(out + (((size_t)a * BB + b) * CC + c) * HWD + ch * 256 + 4 * q) = v;
    }
}

extern "C" void kernel_launch(void* const* d_in, const int* in_sizes, int n_in,
                              void* d_out, int out_size, void* d_ws, size_t ws_size,
                              hipStream_t stream) {
    const float* x = (const float*)d_in[0];
    const float* w = (const float*)d_in[1];
    float* outp = (float*)d_out;
    float* Gp   = (float*)d_ws;                 // 512*1024 floats = 2 MB
    float* Ahat = Gp + (size_t)512 * 1024;      // 128*1024 floats = 512 KB

    hipLaunchKernelGGL(k_gram,    dim3(512),  dim3(256), 0, stream, x, Gp);
    hipLaunchKernelGGL(k_softmax, dim3(128),  dim3(64),  0, stream, Gp, w, Ahat);
    hipLaunchKernelGGL(k_pv,      dim3(2048), dim3(256), 0, stream, x, Ahat, outp);
}

// Round 2
// 44.178 us; speedup vs baseline: 1.2016x; 1.2016x over previous
//
#include <hip/hip_runtime.h>

typedef __attribute__((ext_vector_type(8))) short bf16x8;
typedef __attribute__((ext_vector_type(4))) float f32x4;

#define BB 4
#define NN 32
#define CC 32
#define HWD 4096
#define AROW ((size_t)CC * HWD)   // stride between n-rows (floats)

__device__ __forceinline__ unsigned cvt_pk_bf16(float lo, float hi) {
    unsigned r;
    asm("v_cvt_pk_bf16_f32 %0, %1, %2" : "=v"(r) : "v"(lo), "v"(hi));
    return r;
}

__device__ __forceinline__ bf16x8 pack8(float4 a, float4 b) {
    union { unsigned u[4]; bf16x8 v; } u;
    u.u[0] = cvt_pk_bf16(a.x, a.y);
    u.u[1] = cvt_pk_bf16(a.z, a.w);
    u.u[2] = cvt_pk_bf16(b.x, b.y);
    u.u[3] = cvt_pk_bf16(b.z, b.w);
    return u.v;
}

// ---- Kernel 1: Gram partials via MFMA, frags straight from global ----
// grid 1024 = 128 bc x 8 splits(512 hw); block 256 (4 waves, each 128 hw)
__global__ __launch_bounds__(256) void k_gram(const float* __restrict__ x,
                                              float* __restrict__ Gp) {
    const int bid = blockIdx.x;
    const int s   = bid & 7;
    const int bc  = bid >> 3;
    const int b   = bc >> 5, c = bc & 31;
    const int tid = threadIdx.x;
    const int w   = tid >> 6, l = tid & 63;
    const int r   = l & 15, g = l >> 4;

    const float* xb = x + ((size_t)b * NN * CC + c) * HWD;
    const int hwbase = s * 512 + w * 128;
    const float* p0 = xb + (size_t)r        * AROW + hwbase + 8 * g;  // rows 0-15
    const float* p1 = xb + (size_t)(r + 16) * AROW + hwbase + 8 * g;  // rows 16-31

    f32x4 acc[2][2];
#pragma unroll
    for (int i = 0; i < 2; ++i)
#pragma unroll
        for (int j = 0; j < 2; ++j)
#pragma unroll
            for (int q = 0; q < 4; ++q) acc[i][j][q] = 0.f;

#pragma unroll
    for (int ch = 0; ch < 4; ++ch) {          // 4 k-chunks of K=32
        const float4 a0 = *(const float4*)(p0 + ch * 32);
        const float4 a1 = *(const float4*)(p0 + ch * 32 + 4);
        const float4 b0 = *(const float4*)(p1 + ch * 32);
        const float4 b1 = *(const float4*)(p1 + ch * 32 + 4);
        const bf16x8 F0 = pack8(a0, a1);
        const bf16x8 F1 = pack8(b0, b1);
        acc[0][0] = __builtin_amdgcn_mfma_f32_16x16x32_bf16(F0, F0, acc[0][0], 0, 0, 0);
        acc[0][1] = __builtin_amdgcn_mfma_f32_16x16x32_bf16(F0, F1, acc[0][1], 0, 0, 0);
        acc[1][0] = __builtin_amdgcn_mfma_f32_16x16x32_bf16(F1, F0, acc[1][0], 0, 0, 0);
        acc[1][1] = __builtin_amdgcn_mfma_f32_16x16x32_bf16(F1, F1, acc[1][1], 0, 0, 0);
    }

    __shared__ float red[4][64][16];
#pragma unroll
    for (int ta = 0; ta < 2; ++ta)
#pragma unroll
        for (int tf = 0; tf < 2; ++tf)
#pragma unroll
            for (int q = 0; q < 4; ++q)
                red[w][l][(ta * 2 + tf) * 4 + q] = acc[ta][tf][q];
    __syncthreads();

    // thread t reduces G elements e=4t..4t+3 across 4 waves, coalesced float4 store
    const int a   = tid >> 3;
    const int f0  = 4 * (tid & 7);
    const int lg  = ((a >> 2) & 3) * 16 + (f0 & 15);
    const int reg = ((a >> 4) * 2 + (f0 >> 4)) * 4 + (a & 3);
    float sv[4];
#pragma unroll
    for (int j = 0; j < 4; ++j) {
        float v = 0.f;
#pragma unroll
        for (int ww = 0; ww < 4; ++ww) v += red[ww][lg + j][reg];
        sv[j] = v;
    }
    *(float4*)&Gp[(size_t)bid * 1024 + 4 * tid] = make_float4(sv[0], sv[1], sv[2], sv[3]);
}

// ---- Kernel 2: reduce 8 splits + scale + softmax + fold wv, emit bf16 Ahat ----
// grid 128 (bc); block 256: thread = (a = t>>3, 4 f at fo = 4*(t&7))
__global__ __launch_bounds__(256) void k_softmax(const float* __restrict__ Gp,
                                                 const float* __restrict__ w,
                                                 unsigned short* __restrict__ Ahat) {
    const int bc = blockIdx.x;
    const int c  = bc & 31;
    const int t  = threadIdx.x;
    const int a  = t >> 3, fo = 4 * (t & 7);

    float gs[4] = {0.f, 0.f, 0.f, 0.f};
#pragma unroll
    for (int s = 0; s < 8; ++s) {
        const float4 v = *(const float4*)&Gp[(size_t)(bc * 8 + s) * 1024 + a * 32 + fo];
        gs[0] += v.x; gs[1] += v.y; gs[2] += v.z; gs[3] += v.w;
    }
    const float wq = w[(a * CC + c) * 3] * 0.015625f;   // 1/sqrt(4096)
    float S[4];
#pragma unroll
    for (int j = 0; j < 4; ++j)
        S[j] = wq * w[((fo + j) * CC + c) * 3 + 1] * gs[j];

    float m = fmaxf(fmaxf(S[0], S[1]), fmaxf(S[2], S[3]));
#pragma unroll
    for (int o = 1; o < 8; o <<= 1) m = fmaxf(m, __shfl_xor(m, o, 64));
    float e[4], sum = 0.f;
#pragma unroll
    for (int j = 0; j < 4; ++j) { e[j] = __expf(S[j] - m); sum += e[j]; }
#pragma unroll
    for (int o = 1; o < 8; o <<= 1) sum += __shfl_xor(sum, o, 64);
    const float inv = 1.f / sum;

    float o0 = e[0] * inv * w[((fo + 0) * CC + c) * 3 + 2];
    float o1 = e[1] * inv * w[((fo + 1) * CC + c) * 3 + 2];
    float o2 = e[2] * inv * w[((fo + 2) * CC + c) * 3 + 2];
    float o3 = e[3] * inv * w[((fo + 3) * CC + c) * 3 + 2];
    uint2 pk = make_uint2(cvt_pk_bf16(o0, o1), cvt_pk_bf16(o2, o3));
    *(uint2*)&Ahat[(size_t)bc * 1024 + a * 32 + fo] = pk;
}

// ---- Kernel 3: out[a,b,c,hw] = sum_f Ahat[a,f]*x[b,f,c,hw] via MFMA, LDS-free ----
// grid 2048 = 128 bc x 16 chunks(256 hw); block 256 (wave = 64 hw = 4 tiles)
__global__ __launch_bounds__(256) void k_pv(const float* __restrict__ x,
                                            const unsigned short* __restrict__ Ahat,
                                            float* __restrict__ out) {
    const int bid   = blockIdx.x;
    const int chunk = bid & 15;
    const int bc    = bid >> 4;
    const int b     = bc >> 5, c = bc & 31;
    const int tid   = threadIdx.x;
    const int w     = tid >> 6, l = tid & 63;
    const int r     = l & 15, g = l >> 4;

    // A-frags: lane holds Ahat[ta*16+r][8g..8g+7], contiguous 16B
    const unsigned short* ab = Ahat + (size_t)bc * 1024;
    const bf16x8 A0 = *(const bf16x8*)(ab + r * 32 + 8 * g);
    const bf16x8 A1 = *(const bf16x8*)(ab + (r + 16) * 32 + 8 * g);

    const float* xb = x + ((size_t)b * NN * CC + c) * HWD + chunk * 256 + w * 64;
    const f32x4 zero = {0.f, 0.f, 0.f, 0.f};

#pragma unroll
    for (int ht = 0; ht < 4; ++ht) {
        const int hw = ht * 16 + r;
        const float* bp = xb + (size_t)(8 * g) * AROW + hw;
        float bf[8];
#pragma unroll
        for (int i = 0; i < 8; ++i) bf[i] = bp[(size_t)i * AROW];
        const bf16x8 B = pack8(make_float4(bf[0], bf[1], bf[2], bf[3]),
                               make_float4(bf[4], bf[5], bf[6], bf[7]));
        f32x4 d0 = __builtin_amdgcn_mfma_f32_16x16x32_bf16(A0, B, zero, 0, 0, 0);
        f32x4 d1 = __builtin_amdgcn_mfma_f32_16x16x32_bf16(A1, B, zero, 0, 0, 0);

        const size_t hwg = (size_t)chunk * 256 + w * 64 + ht * 16 + r;
#pragma unroll
        for (int q = 0; q < 4; ++q) {
            const int arow0 = g * 4 + q;
            out[(((size_t)arow0 * BB + b) * CC + c) * HWD + hwg]        = d0[q];
            out[(((size_t)(arow0 + 16) * BB + b) * CC + c) * HWD + hwg] = d1[q];
        }
    }
}

extern "C" void kernel_launch(void* const* d_in, const int* in_sizes, int n_in,
                              void* d_out, int out_size, void* d_ws, size_t ws_size,
                              hipStream_t stream) {
    const float* x = (const float*)d_in[0];
    const float* w = (const float*)d_in[1];
    float* outp = (float*)d_out;
    float* Gp = (float*)d_ws;                                   // 1024*1024 f32 = 4 MB
    unsigned short* Ahat = (unsigned short*)((char*)d_ws + (size_t)4 * 1024 * 1024); // 256 KB

    hipLaunchKernelGGL(k_gram,    dim3(1024), dim3(256), 0, stream, x, Gp);
    hipLaunchKernelGGL(k_softmax, dim3(128),  dim3(256), 0, stream, Gp, w, Ahat);
    hipLaunchKernelGGL(k_pv,      dim3(2048), dim3(256), 0, stream, x, Ahat, outp);
}